// Round 11
// baseline (387.061 us; speedup 1.0000x reference)
//
#include <hip/hip_runtime.h>

// CrossAttention: B=16, Sq=4096, Dm=512, Skv=77, Dc=768, H=8, Dh=64, inner=512
// Single-pass fp16 MFMA pipeline.
//   0. pad_fill : zero vT si-pad + kbuf row-pad
//   1. transpose4: all W* fp32 [K][512] -> fp16 [512][K] in one launch  (ws)
//   2. gemm_ctx OUT_H : k = ctx@Wk -> fp16 [1240pad][512]               (ws)
//      gemm_ctx OUT_HT: v = ctx@Wv -> Vt fp16 [16][512][96pad]          (ws)
//   3. qattn    : q = x@Wq computed INTO LDS (never hits HBM), then
//                 MFMA attention per head -> attnA fp16                  (ws)
//                 q-GEMM uses the R9-proven conservative loop:
//                 A reg-staged issue-early + B gl_lds depth-1 + __syncthreads
//   4. gemm_h16 OUT_F32+bias: out = attn@Wout + bout -> fp32            (d_out)

typedef unsigned short u16;
typedef unsigned int u32;
typedef _Float16 f16;
typedef __attribute__((ext_vector_type(8))) _Float16 half8;
typedef __attribute__((ext_vector_type(4))) _Float16 half4;
typedef __attribute__((ext_vector_type(4))) float f32x4;

__device__ __forceinline__ f32x4 mfma16h(half8 a, half8 b, f32x4 c) {
    return __builtin_amdgcn_mfma_f32_16x16x32_f16(a, b, c, 0, 0, 0);
}
// async global->LDS, 16B per lane; LDS dest = wave-uniform base + lane*16
__device__ __forceinline__ void gl_lds16(const f16* g, f16* l) {
    __builtin_amdgcn_global_load_lds(
        (const __attribute__((address_space(1))) void*)g,
        (__attribute__((address_space(3))) void*)l, 16, 0, 0);
}

// ---------------- pad fill ----------------
__global__ __launch_bounds__(256) void pad_fill(
    f16* __restrict__ vT, f16* __restrict__ kbuf)
{
    const int nv = 16 * 512 * 19;
    int i = blockIdx.x * 256 + threadIdx.x;
    if (i < nv) {
        int g = i / 19, s = i - g * 19;
        vT[(size_t)g * 96 + 77 + s] = (f16)0.f;
    } else {
        int j = i - nv;
        if (j < 8 * 512) kbuf[(size_t)1232 * 512 + j] = (f16)0.f;
    }
}

// ---------------- all 4 weight transposes -> fp16, one launch ----------------
__global__ __launch_bounds__(256) void transpose4(
    const float* __restrict__ Wq, const float* __restrict__ Wk,
    const float* __restrict__ Wv, const float* __restrict__ Wo,
    f16* __restrict__ WqT, f16* __restrict__ WkT,
    f16* __restrict__ WvT, f16* __restrict__ WoT)
{
    int idx = blockIdx.x * 256 + threadIdx.x;
    const float* W; f16* T; int K; int base;
    if (idx < 262144)        { W = Wq; T = WqT; K = 512; base = 0; }
    else if (idx < 655360)   { W = Wk; T = WkT; K = 768; base = 262144; }
    else if (idx < 1048576)  { W = Wv; T = WvT; K = 768; base = 655360; }
    else if (idx < 1310720)  { W = Wo; T = WoT; K = 512; base = 1048576; }
    else return;
    int j = idx - base;
    int n = j / K, k = j - n * K;
    T[j] = (f16)W[(size_t)k * 512 + n];
}

#define OUT_F32 0
#define OUT_H   1
#define OUT_HT  2

// ---------------- fused q-proj + attention ----------------
// grid dim3(64, 16) = (qtile of 64 rows, batch), block 256 (4 waves).
// Per chunk c (q cols c*256..+255 = heads c*4..c*4+3):
//   q-GEMM 64x256x512 (R9-proven loop) -> sQ LDS; attention for 4 heads.
__global__ __launch_bounds__(256) void qattn(
    const float* __restrict__ x, const f16* __restrict__ WqT,
    const f16* __restrict__ kbuf, const f16* __restrict__ vT,
    f16* __restrict__ attnA)
{
    __shared__ f16 sA[2][64 * 32];     // x tile f16, 4 KB each
    __shared__ f16 sB[2][256 * 32];    // WqT tile, 16 KB each
    __shared__ f16 sQ[64 * 264];       // q chunk [64][256 pad 264] (33.75 KB)

    const int t = threadIdx.x;
    const int lane = t & 63;
    const int w = t >> 6;
    const int wr = w >> 1, wc = w & 1;   // gemm: 2x2 waves of 32x128
    const int ar = lane & 15;
    const int kg = lane >> 4;
    const int kc = kg << 3;

    const int b = blockIdx.y;
    const int row0 = blockIdx.x * 64;
    const size_t xbase = ((size_t)b * 4096 + row0) * 512;

    // A staging: thread t -> row t>>2 (0..63), f32 col (t&3)*8
    const int arow = t >> 2;
    const int acol = (t & 3) << 3;
    // B staging: wave w stages 16-row chunks ci = w*4..w*4+3
    const int brow = lane >> 2;
    const int bcol = (lane & 3) << 3;

    f16* myP = &sB[0][0] + w * 16 * 104;   // P overlay on sB[0] (attn phase only)

    #pragma unroll 1
    for (int chunk = 0; chunk < 2; ++chunk) {
        const int c0 = chunk << 8;

        f32x4 acc[2][8] = {};
        f32x4 rA0, rA1;

        auto LOAD_A = [&](int kt) {
            const float* p = x + xbase + (size_t)arow * 512 + (kt << 5) + acol;
            rA0 = *(const f32x4*)(p);
            rA1 = *(const f32x4*)(p + 4);
        };
        auto WRITE_A = [&](int buf) {
            half8 h = { (f16)rA0.x, (f16)rA0.y, (f16)rA0.z, (f16)rA0.w,
                        (f16)rA1.x, (f16)rA1.y, (f16)rA1.z, (f16)rA1.w };
            *(half8*)(&sA[buf][arow * 32 + acol]) = h;
        };
        auto STAGE_B = [&](int buf, int kt) {
            #pragma unroll
            for (int j = 0; j < 4; ++j) {
                const int ci = w * 4 + j;
                gl_lds16(WqT + (size_t)(c0 + ci * 16 + brow) * 512 + (kt << 5) + bcol,
                         &sB[buf][ci * 512]);
            }
        };

        LOAD_A(0);
        STAGE_B(0, 0);
        WRITE_A(0);
        __syncthreads();

        int cur = 0;
        #pragma unroll
        for (int kt = 0; kt < 16; ++kt) {
            // issue next tile's loads early; they fly under ds_read + MFMA
            if (kt + 1 < 16) {
                LOAD_A(kt + 1);
                STAGE_B(cur ^ 1, kt + 1);
            }

            half8 fa[2], fb[8];
            #pragma unroll
            for (int m = 0; m < 2; ++m)
                fa[m] = *(const half8*)(&sA[cur][(wr * 32 + m * 16 + ar) * 32 + kc]);
            #pragma unroll
            for (int n = 0; n < 8; ++n)
                fb[n] = *(const half8*)(&sB[cur][(wc * 128 + n * 16 + ar) * 32 + kc]);

            __builtin_amdgcn_s_setprio(1);
            #pragma unroll
            for (int m = 0; m < 2; ++m)
                #pragma unroll
                for (int n = 0; n < 8; ++n)
                    acc[m][n] = mfma16h(fa[m], fb[n], acc[m][n]);
            __builtin_amdgcn_s_setprio(0);

            if (kt + 1 < 16) WRITE_A(cur ^ 1);   // vmcnt wait lands after MFMA
            __syncthreads();
            cur ^= 1;
        }

        // epilogue: acc -> sQ  (cols 0..255 = q cols c0..c0+255)
        #pragma unroll
        for (int m = 0; m < 2; ++m)
            #pragma unroll
            for (int n = 0; n < 8; ++n)
                #pragma unroll
                for (int r = 0; r < 4; ++r)
                    sQ[(wr * 32 + m * 16 + kg * 4 + r) * 264 + wc * 128 + n * 16 + ar]
                        = (f16)acc[m][n][r];
        __syncthreads();   // q visible to all waves; sB free for P overlay

        // P pad zero (wave-private region), once per chunk
        for (int i = lane; i < 16 * 12; i += 64) {
            int row = i / 12, c = 80 + (i % 12) * 2;
            *(u32*)(myP + row * 104 + c) = 0;
        }

        // ---- attention: heads chunk*4..+3; wave w owns rows w*16..+15 ----
        const int wrow = w * 16;
        #pragma unroll 1
        for (int hh = 0; hh < 4; ++hh) {
            const int head = (chunk << 2) + hh;
            // scores [16 q][80 si]
            f32x4 accs[5] = {};
            #pragma unroll
            for (int ks = 0; ks < 2; ++ks) {
                half8 ah = *(const half8*)(&sQ[(wrow + ar) * 264 + hh * 64 + ks * 32 + kc]);
                #pragma unroll
                for (int n = 0; n < 5; ++n) {
                    half8 bh = *(const half8*)(kbuf +
                        (size_t)(b * 77 + n * 16 + ar) * 512 + head * 64 + ks * 32 + kc);
                    accs[n] = mfma16h(ah, bh, accs[n]);
                }
            }
            // softmax (row = kg*4 + r; 16-lane-group reduce)
            #pragma unroll
            for (int r = 0; r < 4; ++r) {
                float mx = -1e30f;
                #pragma unroll
                for (int n = 0; n < 5; ++n) {
                    float v = accs[n][r] * 0.125f;
                    if (n == 4 && ar >= 13) v = -1e30f;   // mask si >= 77
                    accs[n][r] = v;
                    mx = fmaxf(mx, v);
                }
                mx = fmaxf(mx, __shfl_xor(mx, 1));
                mx = fmaxf(mx, __shfl_xor(mx, 2));
                mx = fmaxf(mx, __shfl_xor(mx, 4));
                mx = fmaxf(mx, __shfl_xor(mx, 8));
                float sum = 0.f;
                #pragma unroll
                for (int n = 0; n < 5; ++n) {
                    float e = __expf(accs[n][r] - mx);
                    accs[n][r] = e;
                    sum += e;
                }
                sum += __shfl_xor(sum, 1);
                sum += __shfl_xor(sum, 2);
                sum += __shfl_xor(sum, 4);
                sum += __shfl_xor(sum, 8);
                float inv = 1.f / sum;
                #pragma unroll
                for (int n = 0; n < 5; ++n) accs[n][r] *= inv;
            }
            // P -> myP (wave-private; within-wave lgkm ordering by compiler)
            #pragma unroll
            for (int n = 0; n < 5; ++n)
                #pragma unroll
                for (int r = 0; r < 4; ++r)
                    myP[(kg * 4 + r) * 104 + n * 16 + ar] = (f16)accs[n][r];
            // PV [16 q][64 d], K-dim 96 (zero-padded)
            f32x4 accp[4] = {};
            #pragma unroll
            for (int ks = 0; ks < 3; ++ks) {
                half8 pa = *(const half8*)(myP + ar * 104 + ks * 32 + kc);
                #pragma unroll
                for (int n = 0; n < 4; ++n) {
                    half8 bh = *(const half8*)(vT +
                        ((size_t)b * 512 + head * 64 + n * 16 + ar) * 96 + ks * 32 + kc);
                    accp[n] = mfma16h(pa, bh, accp[n]);
                }
            }
            // store attn fp16
            #pragma unroll
            for (int n = 0; n < 4; ++n)
                #pragma unroll
                for (int r = 0; r < 4; ++r)
                    attnA[((size_t)b * 4096 + row0 + wrow + kg * 4 + r) * 512
                          + head * 64 + n * 16 + ar] = (f16)accp[n][r];
        }
        __syncthreads();   // all waves done with P/sQ before next chunk stages sB
    }
}

// ---------------- big fp16 GEMM (R6 structure): gl_lds dbuf staging --------
template<bool BIAS, int OUTM>
__global__ __launch_bounds__(256) void gemm_h16(
    const f16* __restrict__ A, const f16* __restrict__ B,
    const float* __restrict__ bias, float* __restrict__ C,
    f16* __restrict__ CHalf, int M, int N, int K)
{
    __shared__ f16 sm[2][2][128 * 32];

    const int t = threadIdx.x;
    const int lane = t & 63;
    const int w = t >> 6;
    const int wr = w >> 1, wc = w & 1;

    const int f = blockIdx.x + gridDim.x * blockIdx.y;
    const int cpx = (gridDim.x * gridDim.y) >> 3;
    const int logical = (f & 7) * cpx + (f >> 3);
    const int m0 = (logical / gridDim.x) * 128;
    const int n0 = (logical % gridDim.x) * 128;

    const int ar = lane & 15;
    const int kc = (lane >> 4) << 3;
    const int srow = lane >> 2;
    const int scol = (lane & 3) << 3;

    f32x4 acc[4][4] = {};

    auto STAGE = [&](int buf, int k0) {
        #pragma unroll
        for (int j = 0; j < 2; ++j) {
            const int ci = w * 2 + j;
            const int r = ci * 16 + srow;
            gl_lds16(A + (size_t)(m0 + r) * K + k0 + scol, &sm[buf][0][ci * 512]);
            gl_lds16(B + (size_t)(n0 + r) * K + k0 + scol, &sm[buf][1][ci * 512]);
        }
    };

    const int nk = K >> 5;
    STAGE(0, 0);
    __syncthreads();

    int cur = 0;
    for (int kt = 0; kt < nk; ++kt) {
        if (kt + 1 < nk) STAGE(cur ^ 1, (kt + 1) << 5);

        const f16* pA = sm[cur][0];
        const f16* pB = sm[cur][1];

        half8 fa[4], fb[4];
        #pragma unroll
        for (int m = 0; m < 4; ++m)
            fa[m] = *(const half8*)(pA + (wr * 64 + m * 16 + ar) * 32 + kc);
        #pragma unroll
        for (int n = 0; n < 4; ++n)
            fb[n] = *(const half8*)(pB + (wc * 64 + n * 16 + ar) * 32 + kc);

        __builtin_amdgcn_s_setprio(1);
        #pragma unroll
        for (int m = 0; m < 4; ++m)
            #pragma unroll
            for (int n = 0; n < 4; ++n)
                acc[m][n] = mfma16h(fa[m], fb[n], acc[m][n]);
        __builtin_amdgcn_s_setprio(0);
        __syncthreads();
        cur ^= 1;
    }

    #pragma unroll
    for (int n = 0; n < 4; ++n) {
        int col = n0 + wc * 64 + n * 16 + ar;
        float bv = 0.f;
        if constexpr (BIAS) bv = bias[col];
        #pragma unroll
        for (int m = 0; m < 4; ++m) {
            #pragma unroll
            for (int r = 0; r < 4; ++r) {
                int row = m0 + wr * 64 + m * 16 + ((lane >> 4) << 2) + r;
                float v = acc[m][n][r] + bv;
                if constexpr (OUTM == OUT_F32) {
                    C[(size_t)row * N + col] = v;
                } else {
                    CHalf[(size_t)row * N + col] = (f16)v;
                }
            }
        }
    }
}

// ---------------- ctx GEMM (kv projections, reg-staged fp32->fp16) ----------
#define PK 40

template<int OUTM>
__global__ __launch_bounds__(256) void gemm_ctx(
    const float* __restrict__ A, const f16* __restrict__ Bt,
    f16* __restrict__ CH, int M, int N, int K)
{
    __shared__ f16 lA[128 * PK];
    __shared__ f16 lB[128 * PK];

    const int t = threadIdx.x;
    const int lane = t & 63;
    const int wid = t >> 6;
    const int wr = wid >> 1, wc = wid & 1;
    const int m0 = blockIdx.x * 128, n0 = blockIdx.y * 128;
    const int ar = lane & 15;
    const int kc = (lane >> 4) << 3;

    f32x4 acc[4][4] = {};

    for (int k0 = 0; k0 < K; k0 += 32) {
        #pragma unroll
        for (int it = 0; it < 4; ++it) {
            int idx = t + it * 256;
            int row = idx >> 3;
            int c4 = (idx & 7) << 2;
            int gr = m0 + row;
            float4 v = make_float4(0.f, 0.f, 0.f, 0.f);
            if (gr < M) v = *(const float4*)(A + (size_t)gr * K + k0 + c4);
            *(half4*)(lA + row * PK + c4) = (half4){(f16)v.x, (f16)v.y, (f16)v.z, (f16)v.w};
        }
        #pragma unroll
        for (int it = 0; it < 2; ++it) {
            int idx = t + it * 256;
            int row = idx >> 2;
            int c8 = (idx & 3) << 3;
            *(half8*)(lB + row * PK + c8) =
                *(const half8*)(Bt + (size_t)(n0 + row) * K + k0 + c8);
        }
        __syncthreads();

        half8 fa[4], fb[4];
        #pragma unroll
        for (int m = 0; m < 4; ++m)
            fa[m] = *(const half8*)(lA + (wr * 64 + m * 16 + ar) * PK + kc);
        #pragma unroll
        for (int n = 0; n < 4; ++n)
            fb[n] = *(const half8*)(lB + (wc * 64 + n * 16 + ar) * PK + kc);
        #pragma unroll
        for (int m = 0; m < 4; ++m)
            #pragma unroll
            for (int n = 0; n < 4; ++n)
                acc[m][n] = mfma16h(fa[m], fb[n], acc[m][n]);
        __syncthreads();
    }

    #pragma unroll
    for (int n = 0; n < 4; ++n) {
        int col = n0 + wc * 64 + n * 16 + ar;
        #pragma unroll
        for (int m = 0; m < 4; ++m) {
            #pragma unroll
            for (int r = 0; r < 4; ++r) {
                int row = m0 + wr * 64 + m * 16 + ((lane >> 4) << 2) + r;
                if (row < M) {
                    float v = acc[m][n][r];
                    if constexpr (OUTM == OUT_H) {
                        CH[(size_t)row * N + col] = (f16)v;
                    } else {
                        int bb = row / 77;
                        int si = row - bb * 77;
                        CH[((size_t)bb * 512 + col) * 96 + si] = (f16)v;
                    }
                }
            }
        }
    }
}

extern "C" void kernel_launch(void* const* d_in, const int* in_sizes, int n_in,
                              void* d_out, int out_size, void* d_ws, size_t ws_size,
                              hipStream_t stream)
{
    const float* x    = (const float*)d_in[0];   // [16,4096,512]
    const float* ctx  = (const float*)d_in[1];   // [16,77,768]
    const float* Wq   = (const float*)d_in[2];   // [512,512]
    const float* Wk   = (const float*)d_in[3];   // [768,512]
    const float* Wv   = (const float*)d_in[4];   // [768,512]
    const float* Wout = (const float*)d_in[5];   // [512,512]
    const float* bout = (const float*)d_in[6];   // [512]

    char* ws = (char*)d_ws;
    size_t off = 0;
    auto alloc = [&](size_t bytes) -> void* {
        void* p = ws + off;
        off += (bytes + 255) & ~(size_t)255;
        return p;
    };
    f16* WqT = (f16*)alloc(512 * 512 * 2);
    f16* WkT = (f16*)alloc(768 * 512 * 2);
    f16* WvT = (f16*)alloc(768 * 512 * 2);
    f16* WoT = (f16*)alloc(512 * 512 * 2);
    f16* kbuf = (f16*)alloc((size_t)1240 * 512 * 2);     // 1232 rows + zero pad
    f16* vT   = (f16*)alloc((size_t)16 * 512 * 96 * 2);  // [b][col][si pad 96]
    f16* attnA = (f16*)alloc((size_t)65536 * 512 * 2);   // attn output (64 MiB)
    (void)ws_size; (void)in_sizes; (void)n_in; (void)out_size;

    // 0. zero pads
    pad_fill<<<dim3(625), dim3(256), 0, stream>>>(vT, kbuf);

    // 1. weight transposes -> fp16 (one launch)
    transpose4<<<dim3(5120), dim3(256), 0, stream>>>(
        Wq, Wk, Wv, Wout, WqT, WkT, WvT, WoT);

    // 2. k/v projections
    gemm_ctx<OUT_H><<<dim3(10, 4), dim3(256), 0, stream>>>(
        ctx, WkT, kbuf, 1232, 512, 768);
    gemm_ctx<OUT_HT><<<dim3(10, 4), dim3(256), 0, stream>>>(
        ctx, WvT, vT, 1232, 512, 768);

    // 3. fused q-proj + attention -> attnA
    qattn<<<dim3(64, 16), dim3(256), 0, stream>>>(x, WqT, kbuf, vT, attnA);

    // 4. output projection + bias -> d_out fp32
    gemm_h16<true, OUT_F32><<<dim3(4, 512), dim3(256), 0, stream>>>(
        attnA, WoT, bout, (float*)d_out, (f16*)nullptr, 65536, 512, 512);
}

// Round 12
// 294.693 us; speedup vs baseline: 1.3134x; 1.3134x over previous
//
#include <hip/hip_runtime.h>

// CrossAttention: B=16, Sq=4096, Dm=512, Skv=77, Dc=768, H=8, Dh=64, inner=512
// Single-pass fp16 MFMA pipeline (R9 structure, 128x256 big-GEMM tiles).
//   0. pad_fill : zero vT si-pad + kbuf row-pad
//   1. transpose4: all W* fp32 [K][512] -> fp16 [512][K] in one launch  (ws)
//   2. gemm_ctx OUT_H : k = ctx@Wk -> fp16 [1240pad][512]               (ws)
//      gemm_ctx OUT_HT: v = ctx@Wv -> Vt fp16 [16][512][96pad]          (ws)
//   3. gemm_x16 : q = x(fp32)@Wq -> fp16 [65536][512]  (cvt fused)      (d_out)
//   4. attn_h16 : MFMA scores + in-reg fp32 softmax + MFMA PV           (ws)
//   5. gemm_h16 : out = attn@Wout + bout -> fp32                        (d_out)
// Big GEMMs: 128x256 tile (32 MFMA per barrier, halves per-iteration latency
// stalls vs 128x128), dbuf LDS, issue-early loads, __syncthreads-only sync.

typedef unsigned short u16;
typedef unsigned int u32;
typedef _Float16 f16;
typedef __attribute__((ext_vector_type(8))) _Float16 half8;
typedef __attribute__((ext_vector_type(4))) _Float16 half4;
typedef __attribute__((ext_vector_type(4))) float f32x4;

__device__ __forceinline__ f32x4 mfma16h(half8 a, half8 b, f32x4 c) {
    return __builtin_amdgcn_mfma_f32_16x16x32_f16(a, b, c, 0, 0, 0);
}
// async global->LDS, 16B per lane; LDS dest = wave-uniform base + lane*16
__device__ __forceinline__ void gl_lds16(const f16* g, f16* l) {
    __builtin_amdgcn_global_load_lds(
        (const __attribute__((address_space(1))) void*)g,
        (__attribute__((address_space(3))) void*)l, 16, 0, 0);
}

// ---------------- pad fill ----------------
__global__ __launch_bounds__(256) void pad_fill(
    f16* __restrict__ vT, f16* __restrict__ kbuf)
{
    const int nv = 16 * 512 * 19;
    int i = blockIdx.x * 256 + threadIdx.x;
    if (i < nv) {
        int g = i / 19, s = i - g * 19;
        vT[(size_t)g * 96 + 77 + s] = (f16)0.f;
    } else {
        int j = i - nv;
        if (j < 8 * 512) kbuf[(size_t)1232 * 512 + j] = (f16)0.f;
    }
}

// ---------------- all 4 weight transposes -> fp16, one launch ----------------
__global__ __launch_bounds__(256) void transpose4(
    const float* __restrict__ Wq, const float* __restrict__ Wk,
    const float* __restrict__ Wv, const float* __restrict__ Wo,
    f16* __restrict__ WqT, f16* __restrict__ WkT,
    f16* __restrict__ WvT, f16* __restrict__ WoT)
{
    int idx = blockIdx.x * 256 + threadIdx.x;
    const float* W; f16* T; int K; int base;
    if (idx < 262144)        { W = Wq; T = WqT; K = 512; base = 0; }
    else if (idx < 655360)   { W = Wk; T = WkT; K = 768; base = 262144; }
    else if (idx < 1048576)  { W = Wv; T = WvT; K = 768; base = 655360; }
    else if (idx < 1310720)  { W = Wo; T = WoT; K = 512; base = 1048576; }
    else return;
    int j = idx - base;
    int n = j / K, k = j - n * K;
    T[j] = (f16)W[(size_t)k * 512 + n];
}

#define OUT_F32 0
#define OUT_H   1
#define OUT_HT  2

// ---------------- q-proj GEMM: fused fp32->fp16, 128x256 tile -------------
// A fp32 [M][K], B fp16 [N][K]; grid dim3(N/256, M/128), block 256.
__global__ __launch_bounds__(256, 2) void gemm_x16(
    const float* __restrict__ A, const f16* __restrict__ B,
    f16* __restrict__ CHalf, int M, int N, int K)
{
    __shared__ f16 sA[2][128 * 32];   // 8 KB each
    __shared__ f16 sB[2][256 * 32];   // 16 KB each (48 KB total)

    const int t = threadIdx.x;
    const int lane = t & 63;
    const int w = t >> 6;
    const int wr = w >> 1, wc = w & 1;   // 2x2 waves of 64x128

    // XCD-chunked bijective swizzle (1024 blocks, %8==0)
    const int f = blockIdx.x + gridDim.x * blockIdx.y;
    const int cpx = (gridDim.x * gridDim.y) >> 3;
    const int logical = (f & 7) * cpx + (f >> 3);
    const int m0 = (logical / gridDim.x) * 128;
    const int n0 = (logical % gridDim.x) * 256;

    const int ar = lane & 15;
    const int kc = (lane >> 4) << 3;

    // A reg staging: thread t -> row t>>1 (0..127), f32 col (t&1)*16
    const int arow = t >> 1;
    const int acol = (t & 1) << 4;
    // B staging via gl_lds: 16 chunks of 16 rows x 32 f16
    const int brow = lane >> 2;
    const int bcol = (lane & 3) << 3;

    f32x4 acc[4][8] = {};
    f32x4 rA[4];

    auto LOAD_A = [&](int kt) {
        const float* p = A + (size_t)(m0 + arow) * K + (kt << 5) + acol;
        #pragma unroll
        for (int j = 0; j < 4; ++j) rA[j] = *(const f32x4*)(p + j * 4);
    };
    auto WRITE_A = [&](int buf) {
        half8 h0 = { (f16)rA[0].x, (f16)rA[0].y, (f16)rA[0].z, (f16)rA[0].w,
                     (f16)rA[1].x, (f16)rA[1].y, (f16)rA[1].z, (f16)rA[1].w };
        half8 h1 = { (f16)rA[2].x, (f16)rA[2].y, (f16)rA[2].z, (f16)rA[2].w,
                     (f16)rA[3].x, (f16)rA[3].y, (f16)rA[3].z, (f16)rA[3].w };
        *(half8*)(&sA[buf][arow * 32 + acol])     = h0;
        *(half8*)(&sA[buf][arow * 32 + acol + 8]) = h1;
    };
    auto STAGE_B = [&](int buf, int kt) {
        #pragma unroll
        for (int j = 0; j < 4; ++j) {
            const int ci = w * 4 + j;            // chunk 0..15 -> rows ci*16..+15
            gl_lds16(B + (size_t)(n0 + ci * 16 + brow) * K + (kt << 5) + bcol,
                     &sB[buf][ci * 512]);
        }
    };

    const int nk = K >> 5;
    LOAD_A(0);
    STAGE_B(0, 0);
    WRITE_A(0);
    __syncthreads();

    int cur = 0;
    for (int kt = 0; kt < nk; ++kt) {
        if (kt + 1 < nk) {
            LOAD_A(kt + 1);
            STAGE_B(cur ^ 1, kt + 1);
        }

        half8 fa[4], fb[8];
        #pragma unroll
        for (int m = 0; m < 4; ++m)
            fa[m] = *(const half8*)(&sA[cur][(wr * 64 + m * 16 + ar) * 32 + kc]);
        #pragma unroll
        for (int n = 0; n < 8; ++n)
            fb[n] = *(const half8*)(&sB[cur][(wc * 128 + n * 16 + ar) * 32 + kc]);

        __builtin_amdgcn_s_setprio(1);
        #pragma unroll
        for (int m = 0; m < 4; ++m)
            #pragma unroll
            for (int n = 0; n < 8; ++n)
                acc[m][n] = mfma16h(fa[m], fb[n], acc[m][n]);
        __builtin_amdgcn_s_setprio(0);

        if (kt + 1 < nk) WRITE_A(cur ^ 1);   // vmcnt wait lands after MFMA
        __syncthreads();
        cur ^= 1;
    }

    #pragma unroll
    for (int n = 0; n < 8; ++n) {
        int col = n0 + wc * 128 + n * 16 + ar;
        #pragma unroll
        for (int m = 0; m < 4; ++m) {
            #pragma unroll
            for (int r = 0; r < 4; ++r) {
                int row = m0 + wr * 64 + m * 16 + ((lane >> 4) << 2) + r;
                CHalf[(size_t)row * N + col] = (f16)acc[m][n][r];
            }
        }
    }
}

// ---------------- out-proj GEMM: fp16, 128x256 tile, gl_lds dbuf -----------
// A fp16 [M][K], B fp16 [N][K]; grid dim3(N/256, M/128), block 256.
__global__ __launch_bounds__(256, 2) void gemm_h16(
    const f16* __restrict__ A, const f16* __restrict__ B,
    const float* __restrict__ bias, float* __restrict__ C,
    int M, int N, int K)
{
    __shared__ f16 sA[2][128 * 32];   // 8 KB each
    __shared__ f16 sB[2][256 * 32];   // 16 KB each (48 KB total)

    const int t = threadIdx.x;
    const int lane = t & 63;
    const int w = t >> 6;
    const int wr = w >> 1, wc = w & 1;

    const int f = blockIdx.x + gridDim.x * blockIdx.y;
    const int cpx = (gridDim.x * gridDim.y) >> 3;
    const int logical = (f & 7) * cpx + (f >> 3);
    const int m0 = (logical / gridDim.x) * 128;
    const int n0 = (logical % gridDim.x) * 256;

    const int ar = lane & 15;
    const int kc = (lane >> 4) << 3;
    const int srow = lane >> 2;
    const int scol = (lane & 3) << 3;

    f32x4 acc[4][8] = {};

    auto STAGE = [&](int buf, int kt) {
        #pragma unroll
        for (int j = 0; j < 2; ++j) {
            const int ci = w * 2 + j;            // A chunks 0..7
            gl_lds16(A + (size_t)(m0 + ci * 16 + srow) * K + (kt << 5) + scol,
                     &sA[buf][ci * 512]);
        }
        #pragma unroll
        for (int j = 0; j < 4; ++j) {
            const int ci = w * 4 + j;            // B chunks 0..15
            gl_lds16(B + (size_t)(n0 + ci * 16 + srow) * K + (kt << 5) + scol,
                     &sB[buf][ci * 512]);
        }
    };

    const int nk = K >> 5;
    STAGE(0, 0);
    __syncthreads();

    int cur = 0;
    for (int kt = 0; kt < nk; ++kt) {
        if (kt + 1 < nk) STAGE(cur ^ 1, kt + 1);

        half8 fa[4], fb[8];
        #pragma unroll
        for (int m = 0; m < 4; ++m)
            fa[m] = *(const half8*)(&sA[cur][(wr * 64 + m * 16 + ar) * 32 + kc]);
        #pragma unroll
        for (int n = 0; n < 8; ++n)
            fb[n] = *(const half8*)(&sB[cur][(wc * 128 + n * 16 + ar) * 32 + kc]);

        __builtin_amdgcn_s_setprio(1);
        #pragma unroll
        for (int m = 0; m < 4; ++m)
            #pragma unroll
            for (int n = 0; n < 8; ++n)
                acc[m][n] = mfma16h(fa[m], fb[n], acc[m][n]);
        __builtin_amdgcn_s_setprio(0);
        __syncthreads();
        cur ^= 1;
    }

    #pragma unroll
    for (int n = 0; n < 8; ++n) {
        int col = n0 + wc * 128 + n * 16 + ar;
        float bv = bias[col];
        #pragma unroll
        for (int m = 0; m < 4; ++m) {
            #pragma unroll
            for (int r = 0; r < 4; ++r) {
                int row = m0 + wr * 64 + m * 16 + ((lane >> 4) << 2) + r;
                C[(size_t)row * N + col] = acc[m][n][r] + bv;
            }
        }
    }
}

// ---------------- ctx GEMM (kv projections, reg-staged fp32->fp16) ----------
#define PK 40

template<int OUTM>
__global__ __launch_bounds__(256) void gemm_ctx(
    const float* __restrict__ A, const f16* __restrict__ Bt,
    f16* __restrict__ CH, int M, int N, int K)
{
    __shared__ f16 lA[128 * PK];
    __shared__ f16 lB[128 * PK];

    const int t = threadIdx.x;
    const int lane = t & 63;
    const int wid = t >> 6;
    const int wr = wid >> 1, wc = wid & 1;
    const int m0 = blockIdx.x * 128, n0 = blockIdx.y * 128;
    const int ar = lane & 15;
    const int kc = (lane >> 4) << 3;

    f32x4 acc[4][4] = {};

    for (int k0 = 0; k0 < K; k0 += 32) {
        #pragma unroll
        for (int it = 0; it < 4; ++it) {
            int idx = t + it * 256;
            int row = idx >> 3;
            int c4 = (idx & 7) << 2;
            int gr = m0 + row;
            float4 v = make_float4(0.f, 0.f, 0.f, 0.f);
            if (gr < M) v = *(const float4*)(A + (size_t)gr * K + k0 + c4);
            *(half4*)(lA + row * PK + c4) = (half4){(f16)v.x, (f16)v.y, (f16)v.z, (f16)v.w};
        }
        #pragma unroll
        for (int it = 0; it < 2; ++it) {
            int idx = t + it * 256;
            int row = idx >> 2;
            int c8 = (idx & 3) << 3;
            *(half8*)(lB + row * PK + c8) =
                *(const half8*)(Bt + (size_t)(n0 + row) * K + k0 + c8);
        }
        __syncthreads();

        half8 fa[4], fb[4];
        #pragma unroll
        for (int m = 0; m < 4; ++m)
            fa[m] = *(const half8*)(lA + (wr * 64 + m * 16 + ar) * PK + kc);
        #pragma unroll
        for (int n = 0; n < 4; ++n)
            fb[n] = *(const half8*)(lB + (wc * 64 + n * 16 + ar) * PK + kc);
        #pragma unroll
        for (int m = 0; m < 4; ++m)
            #pragma unroll
            for (int n = 0; n < 4; ++n)
                acc[m][n] = mfma16h(fa[m], fb[n], acc[m][n]);
        __syncthreads();
    }

    #pragma unroll
    for (int n = 0; n < 4; ++n) {
        int col = n0 + wc * 64 + n * 16 + ar;
        #pragma unroll
        for (int m = 0; m < 4; ++m) {
            #pragma unroll
            for (int r = 0; r < 4; ++r) {
                int row = m0 + wr * 64 + m * 16 + ((lane >> 4) << 2) + r;
                if (row < M) {
                    float v = acc[m][n][r];
                    if constexpr (OUTM == OUT_H) {
                        CH[(size_t)row * N + col] = (f16)v;
                    } else {
                        int bb = row / 77;
                        int si = row - bb * 77;
                        CH[((size_t)bb * 512 + col) * 96 + si] = (f16)v;
                    }
                }
            }
        }
    }
}

// ---------------- MFMA attention (fp16 inputs, fp32 softmax) ----------------
// grid (Sq/128, H, B), block 256 (4 waves, 32 q-rows each).
__global__ __launch_bounds__(256) void attn_h16(
    const f16* __restrict__ q, const f16* __restrict__ k,
    const f16* __restrict__ vT, f16* __restrict__ outA)
{
    constexpr int PST = 104;   // P LDS stride (f16): rows 16B-aligned
    __shared__ f16 sP[4 * 32 * PST];

    const int t = threadIdx.x;
    const int lane = t & 63;
    const int w = t >> 6;
    const int ar = lane & 15;
    const int kg = lane >> 4;
    const int kc = kg << 3;
    const int b = blockIdx.z, head = blockIdx.y;
    const size_t qrow0 = (size_t)b * 4096 + blockIdx.x * 128 + w * 32;

    // ---- scores [32 q][80 si], K-dim = 64 ----
    f32x4 accs[2][5] = {};
    #pragma unroll
    for (int ks = 0; ks < 2; ++ks) {
        const int d = head * 64 + ks * 32 + kc;
        half8 ah[2];
        #pragma unroll
        for (int m = 0; m < 2; ++m)
            ah[m] = *(const half8*)(q + (qrow0 + m * 16 + ar) * 512 + d);
        #pragma unroll
        for (int n = 0; n < 5; ++n) {
            half8 bh = *(const half8*)(k + ((size_t)(b * 77 + n * 16 + ar)) * 512 + d);
            #pragma unroll
            for (int m = 0; m < 2; ++m)
                accs[m][n] = mfma16h(ah[m], bh, accs[m][n]);
        }
    }

    // ---- softmax in registers (rows on 16-lane groups) ----
    #pragma unroll
    for (int m = 0; m < 2; ++m) {
        #pragma unroll
        for (int r = 0; r < 4; ++r) {
            float mx = -1e30f;
            #pragma unroll
            for (int n = 0; n < 5; ++n) {
                float v = accs[m][n][r] * 0.125f;          // * D_HEAD^-0.5
                if (n == 4 && ar >= 13) v = -1e30f;        // mask si >= 77
                accs[m][n][r] = v;
                mx = fmaxf(mx, v);
            }
            mx = fmaxf(mx, __shfl_xor(mx, 1));
            mx = fmaxf(mx, __shfl_xor(mx, 2));
            mx = fmaxf(mx, __shfl_xor(mx, 4));
            mx = fmaxf(mx, __shfl_xor(mx, 8));
            float sum = 0.f;
            #pragma unroll
            for (int n = 0; n < 5; ++n) {
                float e = __expf(accs[m][n][r] - mx);
                accs[m][n][r] = e;
                sum += e;
            }
            sum += __shfl_xor(sum, 1);
            sum += __shfl_xor(sum, 2);
            sum += __shfl_xor(sum, 4);
            sum += __shfl_xor(sum, 8);
            float inv = 1.f / sum;
            #pragma unroll
            for (int n = 0; n < 5; ++n) accs[m][n][r] *= inv;
        }
    }

    // ---- P -> LDS fp16, zero-pad cols 80..103 ----
    f16* myP = sP + w * 32 * PST;
    for (int i = lane; i < 32 * 12; i += 64) {
        int row = i / 12, c = 80 + (i % 12) * 2;
        *(u32*)(myP + row * PST + c) = 0;
    }
    #pragma unroll
    for (int m = 0; m < 2; ++m)
        #pragma unroll
        for (int n = 0; n < 5; ++n)
            #pragma unroll
            for (int r = 0; r < 4; ++r)
                myP[(m * 16 + kg * 4 + r) * PST + n * 16 + ar] = (f16)accs[m][n][r];
    __syncthreads();

    // ---- PV [32 q][64 d], K-dim = 96 (zero-padded) ----
    f32x4 accp[2][4] = {};
    #pragma unroll
    for (int ks = 0; ks < 3; ++ks) {
        half8 pa[2];
        #pragma unroll
        for (int m = 0; m < 2; ++m)
            pa[m] = *(const half8*)(myP + (m * 16 + ar) * PST + ks * 32 + kc);
        #pragma unroll
        for (int n = 0; n < 4; ++n) {
            half8 bh = *(const half8*)(vT + ((size_t)b * 512 + head * 64 + n * 16 + ar) * 96 + ks * 32 + kc);
            #pragma unroll
            for (int m = 0; m < 2; ++m)
                accp[m][n] = mfma16h(pa[m], bh, accp[m][n]);
        }
    }

    // ---- store attn output fp16 ----
    #pragma unroll
    for (int m = 0; m < 2; ++m)
        #pragma unroll
        for (int n = 0; n < 4; ++n)
            #pragma unroll
            for (int r = 0; r < 4; ++r)
                outA[(qrow0 + m * 16 + kg * 4 + r) * 512 + head * 64 + n * 16 + ar]
                    = (f16)accp[m][n][r];
}

extern "C" void kernel_launch(void* const* d_in, const int* in_sizes, int n_in,
                              void* d_out, int out_size, void* d_ws, size_t ws_size,
                              hipStream_t stream)
{
    const float* x    = (const float*)d_in[0];   // [16,4096,512]
    const float* ctx  = (const float*)d_in[1];   // [16,77,768]
    const float* Wq   = (const float*)d_in[2];   // [512,512]
    const float* Wk   = (const float*)d_in[3];   // [768,512]
    const float* Wv   = (const float*)d_in[4];   // [768,512]
    const float* Wout = (const float*)d_in[5];   // [512,512]
    const float* bout = (const float*)d_in[6];   // [512]

    char* ws = (char*)d_ws;
    size_t off = 0;
    auto alloc = [&](size_t bytes) -> void* {
        void* p = ws + off;
        off += (bytes + 255) & ~(size_t)255;
        return p;
    };
    f16* WqT = (f16*)alloc(512 * 512 * 2);
    f16* WkT = (f16*)alloc(768 * 512 * 2);
    f16* WvT = (f16*)alloc(768 * 512 * 2);
    f16* WoT = (f16*)alloc(512 * 512 * 2);
    f16* kbuf = (f16*)alloc((size_t)1240 * 512 * 2);     // 1232 rows + zero pad
    f16* vT   = (f16*)alloc((size_t)16 * 512 * 96 * 2);  // [b][col][si pad 96]
    f16* attnA = (f16*)alloc((size_t)65536 * 512 * 2);   // attn output (64 MiB)
    (void)ws_size; (void)in_sizes; (void)n_in; (void)out_size;

    // q fp16 lives in d_out (67 MB of 128 MB), dead before final GEMM writes
    f16* qh = (f16*)d_out;

    // 0. zero pads
    pad_fill<<<dim3(625), dim3(256), 0, stream>>>(vT, kbuf);

    // 1. weight transposes -> fp16 (one launch)
    transpose4<<<dim3(5120), dim3(256), 0, stream>>>(
        Wq, Wk, Wv, Wout, WqT, WkT, WvT, WoT);

    // 2. k/v projections
    gemm_ctx<OUT_H><<<dim3(10, 4), dim3(256), 0, stream>>>(
        ctx, WkT, kbuf, 1232, 512, 768);
    gemm_ctx<OUT_HT><<<dim3(10, 4), dim3(256), 0, stream>>>(
        ctx, WvT, vT, 1232, 512, 768);

    // 3. q projection (cvt fused): x fp32 @ WqT -> q fp16 in d_out
    gemm_x16<<<dim3(2, 512), dim3(256), 0, stream>>>(
        x, WqT, qh, 65536, 512, 512);

    // 4. attention -> attn fp16
    attn_h16<<<dim3(32, 8, 16), dim3(256), 0, stream>>>(qh, kbuf, vT, attnA);

    // 5. output projection + bias -> d_out fp32
    gemm_h16<<<dim3(2, 512), dim3(256), 0, stream>>>(
        attnA, WoT, bout, (float*)d_out, 65536, 512, 512);
}